// Round 1
// baseline (198.609 us; speedup 1.0000x reference)
//
#include <hip/hip_runtime.h>

// Problem constants (reference: B=2, N=2048, DIM=512, H=8, DH=64)
constexpr int kB   = 2;
constexpr int kN   = 2048;
constexpr int kDIM = 512;
constexpr int kH   = 8;
constexpr int kDH  = 64;
constexpr int kBH  = kB * kH;          // 16
constexpr int NROWS = kB * kN;         // 4096
constexpr int CHUNK = 64;
constexpr int NCH   = kN / CHUNK;      // 32
constexpr int CBSTRIDE = kDH * kDH + kDH;  // 4160 floats per (bh,chunk): S (4096) + z (64)
constexpr float kEPS = 1e-3f;

// ---------------------------------------------------------------------------
// Kernel 1: fused QKV projection.  C = x @ [Wq|Wk|Wv], relu+eps on q,k.
// Output scattered to q/k/v buffers laid out [bh][n][dh].
// grid = (NROWS/64, 24); block = 256.  Each col-block of 64 = one (which,h).
// ---------------------------------------------------------------------------
__global__ __launch_bounds__(256)
void qkv_gemm_kernel(const float* __restrict__ x,
                     const float* __restrict__ Wq,
                     const float* __restrict__ Wk,
                     const float* __restrict__ Wv,
                     float* __restrict__ qb,
                     float* __restrict__ kb,
                     float* __restrict__ vb)
{
    const int bm = blockIdx.x;          // row tile
    const int bn = blockIdx.y;          // 0..23
    const int which = bn >> 3;          // 0=q 1=k 2=v
    const int h = bn & 7;
    const float* W = (which == 0) ? Wq : (which == 1) ? Wk : Wv;
    float* dst = (which == 0) ? qb : (which == 1) ? kb : vb;

    const int t = threadIdx.x;
    const int tx = t & 15, ty = t >> 4;

    __shared__ float as[16][65];        // [kk][m], padded
    __shared__ float bs[16][68];        // [kk][n], padded

    float acc[4][4] = {};
    const int m0 = bm * 64;
    const int n0 = h * 64;

    for (int k0 = 0; k0 < kDIM; k0 += 16) {
        {   // A tile: 64 rows x 16 k
            int row = t >> 2;
            int cg  = (t & 3) * 4;
            const float4 a4 = *(const float4*)(&x[(size_t)(m0 + row) * kDIM + k0 + cg]);
            as[cg + 0][row] = a4.x; as[cg + 1][row] = a4.y;
            as[cg + 2][row] = a4.z; as[cg + 3][row] = a4.w;
        }
        {   // B tile: 16 k x 64 cols
            int kr = t >> 4;
            int cg = (t & 15) * 4;
            const float4 b4 = *(const float4*)(&W[(size_t)(k0 + kr) * kDIM + n0 + cg]);
            bs[kr][cg + 0] = b4.x; bs[kr][cg + 1] = b4.y;
            bs[kr][cg + 2] = b4.z; bs[kr][cg + 3] = b4.w;
        }
        __syncthreads();
        #pragma unroll
        for (int kk = 0; kk < 16; ++kk) {
            float ar[4], br[4];
            #pragma unroll
            for (int i = 0; i < 4; ++i) ar[i] = as[kk][ty * 4 + i];
            #pragma unroll
            for (int j = 0; j < 4; ++j) br[j] = bs[kk][tx * 4 + j];
            #pragma unroll
            for (int i = 0; i < 4; ++i)
                #pragma unroll
                for (int j = 0; j < 4; ++j)
                    acc[i][j] += ar[i] * br[j];
        }
        __syncthreads();
    }

    #pragma unroll
    for (int i = 0; i < 4; ++i) {
        int r = m0 + ty * 4 + i;            // global row = b*2048 + n
        int b = r >> 11, n = r & 2047;
        float v0 = acc[i][0], v1 = acc[i][1], v2 = acc[i][2], v3 = acc[i][3];
        if (which < 2) {                    // relu + eps on q and k
            v0 = fmaxf(v0, 0.f) + kEPS; v1 = fmaxf(v1, 0.f) + kEPS;
            v2 = fmaxf(v2, 0.f) + kEPS; v3 = fmaxf(v3, 0.f) + kEPS;
        }
        float4 o; o.x = v0; o.y = v1; o.z = v2; o.w = v3;
        *(float4*)(dst + ((size_t)(b * kH + h) * kN + n) * kDH + tx * 4) = o;
    }
}

// ---------------------------------------------------------------------------
// Kernel 2: per-chunk sums  S_c[d][e] = sum_n k[n][d] v[n][e],  z_c[d] = sum_n k[n][d]
// grid = (NCH, BH); block = 256.
// ---------------------------------------------------------------------------
__global__ __launch_bounds__(256)
void chunk_sum_kernel(const float* __restrict__ kb, const float* __restrict__ vb,
                      float* __restrict__ cbuf)
{
    const int ch = blockIdx.x, bh = blockIdx.y;
    const int t = threadIdx.x;
    const int tx = t & 15, ty = t >> 4;

    __shared__ float ks[64][65];
    __shared__ float vs[64][68];

    const float* kp = kb + ((size_t)bh * kN + (size_t)ch * CHUNK) * kDH;
    const float* vp = vb + ((size_t)bh * kN + (size_t)ch * CHUNK) * kDH;

    #pragma unroll
    for (int it = 0; it < 4; ++it) {
        int idx = it * 1024 + t * 4;
        int row = idx >> 6, col = idx & 63;
        float4 k4 = *(const float4*)(kp + (size_t)row * kDH + col);
        ks[row][col + 0] = k4.x; ks[row][col + 1] = k4.y;
        ks[row][col + 2] = k4.z; ks[row][col + 3] = k4.w;
        float4 v4 = *(const float4*)(vp + (size_t)row * kDH + col);
        vs[row][col + 0] = v4.x; vs[row][col + 1] = v4.y;
        vs[row][col + 2] = v4.z; vs[row][col + 3] = v4.w;
    }
    __syncthreads();

    float acc[4][4] = {};
    for (int n = 0; n < 64; ++n) {
        float kr[4], vr[4];
        #pragma unroll
        for (int i = 0; i < 4; ++i) kr[i] = ks[n][ty * 4 + i];
        #pragma unroll
        for (int j = 0; j < 4; ++j) vr[j] = vs[n][tx * 4 + j];
        #pragma unroll
        for (int i = 0; i < 4; ++i)
            #pragma unroll
            for (int j = 0; j < 4; ++j)
                acc[i][j] += kr[i] * vr[j];
    }

    float* out = cbuf + ((size_t)bh * NCH + ch) * CBSTRIDE;
    #pragma unroll
    for (int i = 0; i < 4; ++i) {
        float4 o; o.x = acc[i][0]; o.y = acc[i][1]; o.z = acc[i][2]; o.w = acc[i][3];
        *(float4*)(out + (size_t)(ty * 4 + i) * kDH + tx * 4) = o;
    }
    if (t < 64) {
        float z = 0.f;
        for (int n = 0; n < 64; ++n) z += ks[n][t];
        out[kDH * kDH + t] = z;
    }
}

// ---------------------------------------------------------------------------
// Kernel 3: exclusive prefix over chunks (in place).  grid = BH; block = 256.
// ---------------------------------------------------------------------------
__global__ __launch_bounds__(256)
void prefix_kernel(float* __restrict__ cbuf)
{
    const int bh = blockIdx.x;
    const int t = threadIdx.x;
    float* base = cbuf + (size_t)bh * NCH * CBSTRIDE;
    for (int i = t; i < CBSTRIDE; i += 256) {
        float acc = 0.f;
        for (int c = 0; c < NCH; ++c) {
            float* p = base + (size_t)c * CBSTRIDE + i;
            float tmp = *p;
            *p = acc;
            acc += tmp;
        }
    }
}

// ---------------------------------------------------------------------------
// Kernel 4: per-chunk output.
//   A = Q K^T (masked m<=n);  O = A V + Q S_pre;  den = rowsum(A) + Q z_pre
//   attn[b][n][h*64+e] = O[n][e] / den[n]
// grid = (NCH, BH); block = 256.
// ---------------------------------------------------------------------------
__global__ __launch_bounds__(256)
void chunk_out_kernel(const float* __restrict__ qb, const float* __restrict__ kb,
                      const float* __restrict__ vb, const float* __restrict__ cbuf,
                      float* __restrict__ attn)
{
    const int ch = blockIdx.x, bh = blockIdx.y;
    const int t = threadIdx.x;
    const int tx = t & 15, ty = t >> 4;

    __shared__ float qs[64][65];
    __shared__ float kvs[64][68];
    __shared__ float asA[64][65];
    __shared__ float denp[64][17];
    __shared__ float denf[64];

    const float* qp = qb + ((size_t)bh * kN + (size_t)ch * CHUNK) * kDH;
    const float* kp = kb + ((size_t)bh * kN + (size_t)ch * CHUNK) * kDH;
    const float* vp = vb + ((size_t)bh * kN + (size_t)ch * CHUNK) * kDH;
    const float* spre = cbuf + ((size_t)bh * NCH + ch) * CBSTRIDE;

    #pragma unroll
    for (int it = 0; it < 4; ++it) {
        int idx = it * 1024 + t * 4;
        int row = idx >> 6, col = idx & 63;
        float4 q4 = *(const float4*)(qp + (size_t)row * kDH + col);
        qs[row][col + 0] = q4.x; qs[row][col + 1] = q4.y;
        qs[row][col + 2] = q4.z; qs[row][col + 3] = q4.w;
        float4 k4 = *(const float4*)(kp + (size_t)row * kDH + col);
        kvs[row][col + 0] = k4.x; kvs[row][col + 1] = k4.y;
        kvs[row][col + 2] = k4.z; kvs[row][col + 3] = k4.w;
    }
    __syncthreads();

    // A = Q K^T  (K-dim = d)
    float acc[4][4] = {};
    for (int d = 0; d < 64; ++d) {
        float qr[4], kr[4];
        #pragma unroll
        for (int i = 0; i < 4; ++i) qr[i] = qs[ty * 4 + i][d];
        #pragma unroll
        for (int j = 0; j < 4; ++j) kr[j] = kvs[tx * 4 + j][d];
        #pragma unroll
        for (int i = 0; i < 4; ++i)
            #pragma unroll
            for (int j = 0; j < 4; ++j)
                acc[i][j] += qr[i] * kr[j];
    }
    __syncthreads();   // all reads of kvs (K) done

    // masked A -> LDS, den partials, and start V load into kvs
    #pragma unroll
    for (int i = 0; i < 4; ++i) {
        float p = 0.f;
        #pragma unroll
        for (int j = 0; j < 4; ++j) {
            float a = (tx * 4 + j <= ty * 4 + i) ? acc[i][j] : 0.f;
            asA[ty * 4 + i][tx * 4 + j] = a;
            p += a;
        }
        denp[ty * 4 + i][tx] = p;
    }
    #pragma unroll
    for (int it = 0; it < 4; ++it) {
        int idx = it * 1024 + t * 4;
        int row = idx >> 6, col = idx & 63;
        float4 v4 = *(const float4*)(vp + (size_t)row * kDH + col);
        kvs[row][col + 0] = v4.x; kvs[row][col + 1] = v4.y;
        kvs[row][col + 2] = v4.z; kvs[row][col + 3] = v4.w;
    }
    __syncthreads();

    if (t < 64) {   // den[n] = sum_m A~[n][m] + sum_d q[n][d] * z_pre[d]
        float dsum = 0.f;
        #pragma unroll
        for (int x2 = 0; x2 < 16; ++x2) dsum += denp[t][x2];
        const float* z = spre + kDH * kDH;
        for (int d = 0; d < 64; ++d) dsum += qs[t][d] * z[d];
        denf[t] = 1.0f / dsum;
    }

    // O = A~ V  +  Q S_pre
    float o[4][4] = {};
    for (int m = 0; m < 64; ++m) {
        float ar[4], vr[4];
        #pragma unroll
        for (int i = 0; i < 4; ++i) ar[i] = asA[ty * 4 + i][m];
        #pragma unroll
        for (int j = 0; j < 4; ++j) vr[j] = kvs[m][tx * 4 + j];
        #pragma unroll
        for (int i = 0; i < 4; ++i)
            #pragma unroll
            for (int j = 0; j < 4; ++j)
                o[i][j] += ar[i] * vr[j];
    }
    for (int d = 0; d < 64; ++d) {
        float qr[4];
        #pragma unroll
        for (int i = 0; i < 4; ++i) qr[i] = qs[ty * 4 + i][d];
        const float4 s4 = *(const float4*)(spre + (size_t)d * kDH + tx * 4);
        #pragma unroll
        for (int i = 0; i < 4; ++i) {
            o[i][0] += qr[i] * s4.x; o[i][1] += qr[i] * s4.y;
            o[i][2] += qr[i] * s4.z; o[i][3] += qr[i] * s4.w;
        }
    }
    __syncthreads();   // denf ready

    const int b = bh >> 3, h = bh & 7;
    #pragma unroll
    for (int i = 0; i < 4; ++i) {
        int n = ch * CHUNK + ty * 4 + i;
        float di = denf[ty * 4 + i];
        float4 st;
        st.x = o[i][0] * di; st.y = o[i][1] * di;
        st.z = o[i][2] * di; st.w = o[i][3] * di;
        *(float4*)(attn + ((size_t)(b * kN + n) * (kH * kDH)) + h * kDH + tx * 4) = st;
    }
}

// ---------------------------------------------------------------------------
// Kernel 5: out = attn @ Wo + bo.  grid = (NROWS/64, DIM/64); block = 256.
// ---------------------------------------------------------------------------
__global__ __launch_bounds__(256)
void out_gemm_kernel(const float* __restrict__ attn, const float* __restrict__ Wo,
                     const float* __restrict__ bo, float* __restrict__ out)
{
    const int bm = blockIdx.x;
    const int bn = blockIdx.y;
    const int t = threadIdx.x;
    const int tx = t & 15, ty = t >> 4;

    __shared__ float as[16][65];
    __shared__ float bs[16][68];

    float acc[4][4] = {};
    const int m0 = bm * 64;
    const int n0 = bn * 64;

    for (int k0 = 0; k0 < kDIM; k0 += 16) {
        {
            int row = t >> 2;
            int cg  = (t & 3) * 4;
            const float4 a4 = *(const float4*)(&attn[(size_t)(m0 + row) * kDIM + k0 + cg]);
            as[cg + 0][row] = a4.x; as[cg + 1][row] = a4.y;
            as[cg + 2][row] = a4.z; as[cg + 3][row] = a4.w;
        }
        {
            int kr = t >> 4;
            int cg = (t & 15) * 4;
            const float4 b4 = *(const float4*)(&Wo[(size_t)(k0 + kr) * kDIM + n0 + cg]);
            bs[kr][cg + 0] = b4.x; bs[kr][cg + 1] = b4.y;
            bs[kr][cg + 2] = b4.z; bs[kr][cg + 3] = b4.w;
        }
        __syncthreads();
        #pragma unroll
        for (int kk = 0; kk < 16; ++kk) {
            float ar[4], br[4];
            #pragma unroll
            for (int i = 0; i < 4; ++i) ar[i] = as[kk][ty * 4 + i];
            #pragma unroll
            for (int j = 0; j < 4; ++j) br[j] = bs[kk][tx * 4 + j];
            #pragma unroll
            for (int i = 0; i < 4; ++i)
                #pragma unroll
                for (int j = 0; j < 4; ++j)
                    acc[i][j] += ar[i] * br[j];
        }
        __syncthreads();
    }

    #pragma unroll
    for (int i = 0; i < 4; ++i) {
        int r = m0 + ty * 4 + i;
        float4 o;
        o.x = acc[i][0] + bo[n0 + tx * 4 + 0];
        o.y = acc[i][1] + bo[n0 + tx * 4 + 1];
        o.z = acc[i][2] + bo[n0 + tx * 4 + 2];
        o.w = acc[i][3] + bo[n0 + tx * 4 + 3];
        *(float4*)(out + (size_t)r * kDIM + n0 + tx * 4) = o;
    }
}

// ---------------------------------------------------------------------------
extern "C" void kernel_launch(void* const* d_in, const int* in_sizes, int n_in,
                              void* d_out, int out_size, void* d_ws, size_t ws_size,
                              hipStream_t stream)
{
    const float* x  = (const float*)d_in[0];
    const float* Wq = (const float*)d_in[1];
    const float* Wk = (const float*)d_in[2];
    const float* Wv = (const float*)d_in[3];
    const float* Wo = (const float*)d_in[4];
    const float* bo = (const float*)d_in[5];
    float* out = (float*)d_out;

    float* ws = (float*)d_ws;
    const size_t qkvsz = (size_t)kBH * kN * kDH;      // 2,097,152 floats each
    float* qb   = ws;
    float* kb   = qb + qkvsz;
    float* vb   = kb + qkvsz;
    float* attn = vb + qkvsz;                          // [4096][512]
    float* cbuf = attn + (size_t)NROWS * kDIM;         // [BH][NCH][4160]

    qkv_gemm_kernel<<<dim3(NROWS / 64, 24), 256, 0, stream>>>(x, Wq, Wk, Wv, qb, kb, vb);
    chunk_sum_kernel<<<dim3(NCH, kBH), 256, 0, stream>>>(kb, vb, cbuf);
    prefix_kernel<<<kBH, 256, 0, stream>>>(cbuf);
    chunk_out_kernel<<<dim3(NCH, kBH), 256, 0, stream>>>(qb, kb, vb, cbuf, attn);
    out_gemm_kernel<<<dim3(NROWS / 64, kDIM / 64), 256, 0, stream>>>(attn, Wo, bo, out);
}

// Round 2
// 68.226 us; speedup vs baseline: 2.9110x; 2.9110x over previous
//
#include <hip/hip_runtime.h>

// Problem constants (reference: B=2, N=2048, DIM=512, H=8, DH=64)
constexpr int kB   = 2;
constexpr int kN   = 2048;
constexpr int kDIM = 512;
constexpr int kH   = 8;
constexpr int kDH  = 64;
constexpr int kBH  = kB * kH;          // 16
constexpr int NROWS = kB * kN;         // 4096
constexpr int CHUNK = 64;
constexpr int NCH   = kN / CHUNK;      // 32
constexpr int CBSTRIDE = kDH * kDH + kDH;  // 4160 floats per (bh,chunk): S (4096) + z (64)
constexpr float kEPS = 1e-3f;

typedef _Float16 f16x8 __attribute__((ext_vector_type(8)));
typedef _Float16 f16x4 __attribute__((ext_vector_type(4)));
typedef float    floatx4 __attribute__((ext_vector_type(4)));

__device__ __forceinline__ void async_copy16(void* lds, const void* g) {
    __builtin_amdgcn_global_load_lds(
        (const __attribute__((address_space(1))) void*)g,
        (__attribute__((address_space(3))) void*)lds,
        16, 0, 0);
}

// ---------------------------------------------------------------------------
// fp32 -> fp16 convert of x (no transpose).  2M elems, 8 per thread.
// ---------------------------------------------------------------------------
__global__ __launch_bounds__(256)
void convert_x_kernel(const float* __restrict__ x, _Float16* __restrict__ xh)
{
    const int i = blockIdx.x * 256 + threadIdx.x;
    const float4 a = *(const float4*)(x + (size_t)i * 8);
    const float4 b = *(const float4*)(x + (size_t)i * 8 + 4);
    f16x8 o;
    o[0] = (_Float16)a.x; o[1] = (_Float16)a.y; o[2] = (_Float16)a.z; o[3] = (_Float16)a.w;
    o[4] = (_Float16)b.x; o[5] = (_Float16)b.y; o[6] = (_Float16)b.z; o[7] = (_Float16)b.w;
    *(f16x8*)(xh + (size_t)i * 8) = o;
}

// ---------------------------------------------------------------------------
// Transpose + convert weights: W[512][512] fp32 -> WT[512][512] fp16 (WT[n][k]).
// z = 0,1,2 -> Wq,Wk,Wv into fused WT[1536][512]; z = 3 -> Wo into WoT.
// 32x32 LDS tile transpose; grid (16,16,4), block 256.
// ---------------------------------------------------------------------------
__global__ __launch_bounds__(256)
void convert_wT_kernel(const float* __restrict__ Wq, const float* __restrict__ Wk,
                       const float* __restrict__ Wv, const float* __restrict__ Wo,
                       _Float16* __restrict__ WT, _Float16* __restrict__ WoT)
{
    __shared__ float tile[32][33];
    const int z = blockIdx.z;
    const float* src = (z == 0) ? Wq : (z == 1) ? Wk : (z == 2) ? Wv : Wo;
    _Float16* dst = (z < 3) ? (WT + (size_t)z * 512 * 512) : WoT;
    const int r0 = blockIdx.y * 32, c0 = blockIdx.x * 32;
    const int tr = threadIdx.x >> 5, tc = threadIdx.x & 31;
    #pragma unroll
    for (int i = 0; i < 4; ++i)
        tile[tr + 8 * i][tc] = src[(size_t)(r0 + tr + 8 * i) * 512 + c0 + tc];
    __syncthreads();
    #pragma unroll
    for (int i = 0; i < 4; ++i)
        dst[(size_t)(c0 + tr + 8 * i) * 512 + r0 + tc] = (_Float16)tile[tc][tr + 8 * i];
}

// ---------------------------------------------------------------------------
// MFMA GEMM: C[M][N] = A[M][K=512] * BT[N][K]^T, fp16 in, fp32 out.
// BM=BN=128, BK=64, 256 threads (4 waves, 2x2 wave grid, 64x64 per wave).
// global_load_lds (16B) staging, XOR-swizzled (slot ^ row&7) source+read.
// MODE 0: qkv epilogue (relu+eps on q,k; scatter to [bh][n][64]).
// MODE 1: out epilogue (+bias, row-major [4096][512]).
// ---------------------------------------------------------------------------
template<int MODE>
__global__ __launch_bounds__(256)
void mfma_gemm_kernel(const _Float16* __restrict__ A,
                      const _Float16* __restrict__ BT,
                      const float* __restrict__ bo,
                      float* __restrict__ o0,
                      float* __restrict__ o1,
                      float* __restrict__ o2)
{
    constexpr int BM = 128, BN = 128, BK = 64, K = 512;
    __shared__ _Float16 As[BM * BK];   // 16 KB, rows of 128 B
    __shared__ _Float16 Bs[BN * BK];   // 16 KB

    const int t = threadIdx.x;
    const int l = t & 63;
    const int w = t >> 6;
    const int wm = w >> 1, wn = w & 1;
    const int m0 = blockIdx.x * BM;
    const int n0 = blockIdx.y * BN;

    const int r15 = l & 15, kq = l >> 4, sw = r15 & 7;

    floatx4 acc[4][4];
    #pragma unroll
    for (int mi = 0; mi < 4; ++mi)
        #pragma unroll
        for (int ni = 0; ni < 4; ++ni)
            acc[mi][ni] = (floatx4){0.f, 0.f, 0.f, 0.f};

    // staging coords: 4 rounds x 256 threads x 16 B = 16 KB (128 rows x 128 B)
    const int srow  = t >> 3;       // 0..31 (row within 32-row group)
    const int sslot = t & 7;        // 16B slot within 128B row

    const char* Abase = (const char*)(A + (size_t)m0 * K);
    const char* Bbase = (const char*)(BT + (size_t)n0 * K);
    char* AsB = (char*)As;
    char* BsB = (char*)Bs;

    const char* ArdB = (const char*)As + (wm * 64 + r15) * 128;
    const char* BrdB = (const char*)Bs + (wn * 64 + r15) * 128;
    const int sw0 = ((kq ^ sw) << 4);
    const int sw1 = (((4 + kq) ^ sw) << 4);

    for (int k0 = 0; k0 < K; k0 += BK) {
        #pragma unroll
        for (int i = 0; i < 4; ++i) {
            const int row = i * 32 + srow;
            const int gsl = sslot ^ (row & 7);   // inverse-swizzled source slot
            async_copy16(AsB + row * 128 + sslot * 16,
                         Abase + (size_t)row * (K * 2) + k0 * 2 + gsl * 16);
            async_copy16(BsB + row * 128 + sslot * 16,
                         Bbase + (size_t)row * (K * 2) + k0 * 2 + gsl * 16);
        }
        __syncthreads();   // drains vmcnt (global_load_lds) + lgkmcnt

        f16x8 af[4][2], bf[4][2];
        #pragma unroll
        for (int i = 0; i < 4; ++i) {
            af[i][0] = *(const f16x8*)(ArdB + i * 2048 + sw0);
            af[i][1] = *(const f16x8*)(ArdB + i * 2048 + sw1);
            bf[i][0] = *(const f16x8*)(BrdB + i * 2048 + sw0);
            bf[i][1] = *(const f16x8*)(BrdB + i * 2048 + sw1);
        }
        #pragma unroll
        for (int kh = 0; kh < 2; ++kh)
            #pragma unroll
            for (int mi = 0; mi < 4; ++mi)
                #pragma unroll
                for (int ni = 0; ni < 4; ++ni)
                    acc[mi][ni] = __builtin_amdgcn_mfma_f32_16x16x32_f16(
                        af[mi][kh], bf[ni][kh], acc[mi][ni], 0, 0, 0);
        __syncthreads();   // all LDS reads done before next stage overwrites
    }

    // Epilogue.  D fragment: row = kq*4 + r, col = r15 (within each 16x16).
    if (MODE == 0) {
        const int which = n0 >> 9;                  // uniform per block
        float* dst = (which == 0) ? o0 : (which == 1) ? o1 : o2;
        #pragma unroll
        for (int ni = 0; ni < 4; ++ni) {
            const int col = n0 + wn * 64 + ni * 16 + r15;
            const int h = (col >> 6) & 7, e = col & 63;
            #pragma unroll
            for (int mi = 0; mi < 4; ++mi) {
                #pragma unroll
                for (int r = 0; r < 4; ++r) {
                    const int row = m0 + wm * 64 + mi * 16 + kq * 4 + r;
                    const int b = row >> 11, n = row & 2047;
                    float v = acc[mi][ni][r];
                    if (which < 2) v = fmaxf(v, 0.f) + kEPS;
                    dst[((size_t)((b << 3) + h) * 2048 + n) * 64 + e] = v;
                }
            }
        }
    } else {
        #pragma unroll
        for (int ni = 0; ni < 4; ++ni) {
            const int col = n0 + wn * 64 + ni * 16 + r15;
            const float bias = bo[col];
            #pragma unroll
            for (int mi = 0; mi < 4; ++mi) {
                const int row = m0 + wm * 64 + mi * 16 + kq * 4;
                #pragma unroll
                for (int r = 0; r < 4; ++r)
                    o0[(size_t)(row + r) * 512 + col] = acc[mi][ni][r] + bias;
            }
        }
    }
}

// ---------------------------------------------------------------------------
// per-chunk sums  S_c[d][e] = sum_n k[n][d] v[n][e],  z_c[d] = sum_n k[n][d]
// grid = (NCH, BH); block = 256.
// ---------------------------------------------------------------------------
__global__ __launch_bounds__(256)
void chunk_sum_kernel(const float* __restrict__ kb, const float* __restrict__ vb,
                      float* __restrict__ cbuf)
{
    const int ch = blockIdx.x, bh = blockIdx.y;
    const int t = threadIdx.x;
    const int tx = t & 15, ty = t >> 4;

    __shared__ float ks[64][65];
    __shared__ float vs[64][68];

    const float* kp = kb + ((size_t)bh * kN + (size_t)ch * CHUNK) * kDH;
    const float* vp = vb + ((size_t)bh * kN + (size_t)ch * CHUNK) * kDH;

    #pragma unroll
    for (int it = 0; it < 4; ++it) {
        int idx = it * 1024 + t * 4;
        int row = idx >> 6, col = idx & 63;
        float4 k4 = *(const float4*)(kp + (size_t)row * kDH + col);
        ks[row][col + 0] = k4.x; ks[row][col + 1] = k4.y;
        ks[row][col + 2] = k4.z; ks[row][col + 3] = k4.w;
        float4 v4 = *(const float4*)(vp + (size_t)row * kDH + col);
        vs[row][col + 0] = v4.x; vs[row][col + 1] = v4.y;
        vs[row][col + 2] = v4.z; vs[row][col + 3] = v4.w;
    }
    __syncthreads();

    float acc[4][4] = {};
    for (int n = 0; n < 64; ++n) {
        float kr[4], vr[4];
        #pragma unroll
        for (int i = 0; i < 4; ++i) kr[i] = ks[n][ty * 4 + i];
        #pragma unroll
        for (int j = 0; j < 4; ++j) vr[j] = vs[n][tx * 4 + j];
        #pragma unroll
        for (int i = 0; i < 4; ++i)
            #pragma unroll
            for (int j = 0; j < 4; ++j)
                acc[i][j] += kr[i] * vr[j];
    }

    float* out = cbuf + ((size_t)bh * NCH + ch) * CBSTRIDE;
    #pragma unroll
    for (int i = 0; i < 4; ++i) {
        float4 o; o.x = acc[i][0]; o.y = acc[i][1]; o.z = acc[i][2]; o.w = acc[i][3];
        *(float4*)(out + (size_t)(ty * 4 + i) * kDH + tx * 4) = o;
    }
    if (t < 64) {
        float z = 0.f;
        for (int n = 0; n < 64; ++n) z += ks[n][t];
        out[kDH * kDH + t] = z;
    }
}

// ---------------------------------------------------------------------------
// exclusive prefix over chunks, one element per thread, register scan.
// grid = (17, BH); block = 256.
// ---------------------------------------------------------------------------
__global__ __launch_bounds__(256)
void prefix_kernel(float* __restrict__ cbuf)
{
    const int bh = blockIdx.y;
    const int i = blockIdx.x * 256 + threadIdx.x;
    if (i >= CBSTRIDE) return;
    float* base = cbuf + (size_t)bh * NCH * CBSTRIDE + i;
    float vals[NCH];
    #pragma unroll
    for (int c = 0; c < NCH; ++c) vals[c] = base[(size_t)c * CBSTRIDE];
    float acc = 0.f;
    #pragma unroll
    for (int c = 0; c < NCH; ++c) {
        float tmp = vals[c];
        base[(size_t)c * CBSTRIDE] = acc;
        acc += tmp;
    }
}

// ---------------------------------------------------------------------------
// per-chunk output (writes attn as fp16 for the out-GEMM).
// grid = (NCH, BH); block = 256.
// ---------------------------------------------------------------------------
__global__ __launch_bounds__(256)
void chunk_out_kernel(const float* __restrict__ qb, const float* __restrict__ kb,
                      const float* __restrict__ vb, const float* __restrict__ cbuf,
                      _Float16* __restrict__ attnh)
{
    const int ch = blockIdx.x, bh = blockIdx.y;
    const int t = threadIdx.x;
    const int tx = t & 15, ty = t >> 4;

    __shared__ float qs[64][65];
    __shared__ float kvs[64][68];
    __shared__ float asA[64][65];
    __shared__ float denp[64][17];
    __shared__ float denf[64];

    const float* qp = qb + ((size_t)bh * kN + (size_t)ch * CHUNK) * kDH;
    const float* kp = kb + ((size_t)bh * kN + (size_t)ch * CHUNK) * kDH;
    const float* vp = vb + ((size_t)bh * kN + (size_t)ch * CHUNK) * kDH;
    const float* spre = cbuf + ((size_t)bh * NCH + ch) * CBSTRIDE;

    #pragma unroll
    for (int it = 0; it < 4; ++it) {
        int idx = it * 1024 + t * 4;
        int row = idx >> 6, col = idx & 63;
        float4 q4 = *(const float4*)(qp + (size_t)row * kDH + col);
        qs[row][col + 0] = q4.x; qs[row][col + 1] = q4.y;
        qs[row][col + 2] = q4.z; qs[row][col + 3] = q4.w;
        float4 k4 = *(const float4*)(kp + (size_t)row * kDH + col);
        kvs[row][col + 0] = k4.x; kvs[row][col + 1] = k4.y;
        kvs[row][col + 2] = k4.z; kvs[row][col + 3] = k4.w;
    }
    __syncthreads();

    // A = Q K^T
    float acc[4][4] = {};
    for (int d = 0; d < 64; ++d) {
        float qr[4], kr[4];
        #pragma unroll
        for (int i = 0; i < 4; ++i) qr[i] = qs[ty * 4 + i][d];
        #pragma unroll
        for (int j = 0; j < 4; ++j) kr[j] = kvs[tx * 4 + j][d];
        #pragma unroll
        for (int i = 0; i < 4; ++i)
            #pragma unroll
            for (int j = 0; j < 4; ++j)
                acc[i][j] += qr[i] * kr[j];
    }
    __syncthreads();   // all reads of kvs (K) done

    #pragma unroll
    for (int i = 0; i < 4; ++i) {
        float p = 0.f;
        #pragma unroll
        for (int j = 0; j < 4; ++j) {
            float a = (tx * 4 + j <= ty * 4 + i) ? acc[i][j] : 0.f;
            asA[ty * 4 + i][tx * 4 + j] = a;
            p += a;
        }
        denp[ty * 4 + i][tx] = p;
    }
    #pragma unroll
    for (int it = 0; it < 4; ++it) {
        int idx = it * 1024 + t * 4;
        int row = idx >> 6, col = idx & 63;
        float4 v4 = *(const float4*)(vp + (size_t)row * kDH + col);
        kvs[row][col + 0] = v4.x; kvs[row][col + 1] = v4.y;
        kvs[row][col + 2] = v4.z; kvs[row][col + 3] = v4.w;
    }
    __syncthreads();

    if (t < 64) {
        float dsum = 0.f;
        #pragma unroll
        for (int x2 = 0; x2 < 16; ++x2) dsum += denp[t][x2];
        const float* z = spre + kDH * kDH;
        for (int d = 0; d < 64; ++d) dsum += qs[t][d] * z[d];
        denf[t] = 1.0f / dsum;
    }

    // O = A~ V + Q S_pre
    float o[4][4] = {};
    for (int m = 0; m < 64; ++m) {
        float ar[4], vr[4];
        #pragma unroll
        for (int i = 0; i < 4; ++i) ar[i] = asA[ty * 4 + i][m];
        #pragma unroll
        for (int j = 0; j < 4; ++j) vr[j] = kvs[m][tx * 4 + j];
        #pragma unroll
        for (int i = 0; i < 4; ++i)
            #pragma unroll
            for (int j = 0; j < 4; ++j)
                o[i][j] += ar[i] * vr[j];
    }
    for (int d = 0; d < 64; ++d) {
        float qr[4];
        #pragma unroll
        for (int i = 0; i < 4; ++i) qr[i] = qs[ty * 4 + i][d];
        const float4 s4 = *(const float4*)(spre + (size_t)d * kDH + tx * 4);
        #pragma unroll
        for (int i = 0; i < 4; ++i) {
            o[i][0] += qr[i] * s4.x; o[i][1] += qr[i] * s4.y;
            o[i][2] += qr[i] * s4.z; o[i][3] += qr[i] * s4.w;
        }
    }
    __syncthreads();   // denf ready

    const int b = bh >> 3, h = bh & 7;
    #pragma unroll
    for (int i = 0; i < 4; ++i) {
        int n = ch * CHUNK + ty * 4 + i;
        float di = denf[ty * 4 + i];
        f16x4 st;
        st[0] = (_Float16)(o[i][0] * di);
        st[1] = (_Float16)(o[i][1] * di);
        st[2] = (_Float16)(o[i][2] * di);
        st[3] = (_Float16)(o[i][3] * di);
        *(f16x4*)(attnh + (((size_t)(b * kN + n)) << 9) + h * 64 + tx * 4) = st;
    }
}

// ---------------------------------------------------------------------------
extern "C" void kernel_launch(void* const* d_in, const int* in_sizes, int n_in,
                              void* d_out, int out_size, void* d_ws, size_t ws_size,
                              hipStream_t stream)
{
    const float* x  = (const float*)d_in[0];
    const float* Wq = (const float*)d_in[1];
    const float* Wk = (const float*)d_in[2];
    const float* Wv = (const float*)d_in[3];
    const float* Wo = (const float*)d_in[4];
    const float* bo = (const float*)d_in[5];
    float* out = (float*)d_out;

    char* ws = (char*)d_ws;
    float*    qb    = (float*)(ws + 0);            //  8,388,608 B  [bh][n][64] f32
    float*    kb    = (float*)(ws + 8388608);      //  8,388,608 B
    float*    vb    = (float*)(ws + 16777216);     //  8,388,608 B
    float*    cbuf  = (float*)(ws + 25165824);     //  8,519,680 B  [bh][ch][4160] f32
    _Float16* xh    = (_Float16*)(ws + 33685504);  //  4,194,304 B  [4096][512] f16
    _Float16* WT    = (_Float16*)(ws + 37879808);  //  1,572,864 B  [1536][512] f16
    _Float16* WoT   = (_Float16*)(ws + 39452672);  //    524,288 B  [512][512] f16
    _Float16* attnh = xh;                          // alias: xh dead after qkv GEMM

    convert_x_kernel<<<1024, 256, 0, stream>>>(x, xh);
    convert_wT_kernel<<<dim3(16, 16, 4), 256, 0, stream>>>(Wq, Wk, Wv, Wo, WT, WoT);
    mfma_gemm_kernel<0><<<dim3(NROWS / 128, 12), 256, 0, stream>>>(xh, WT, nullptr, qb, kb, vb);
    chunk_sum_kernel<<<dim3(NCH, kBH), 256, 0, stream>>>(kb, vb, cbuf);
    prefix_kernel<<<dim3(17, kBH), 256, 0, stream>>>(cbuf);
    chunk_out_kernel<<<dim3(NCH, kBH), 256, 0, stream>>>(qb, kb, vb, cbuf, attnh);
    mfma_gemm_kernel<1><<<dim3(NROWS / 128, 4), 256, 0, stream>>>(attnh, WoT, bo, out, nullptr, nullptr);
}

// Round 3
// 56.481 us; speedup vs baseline: 3.5164x; 1.2079x over previous
//
#include <hip/hip_runtime.h>

// Problem constants (reference: B=2, N=2048, DIM=512, H=8, DH=64)
constexpr int kB   = 2;
constexpr int kN   = 2048;
constexpr int kDIM = 512;
constexpr int kH   = 8;
constexpr int kDH  = 64;
constexpr int kBH  = kB * kH;          // 16
constexpr int NROWS = kB * kN;         // 4096
constexpr int CHUNK = 64;
constexpr int NCH   = kN / CHUNK;      // 32
constexpr int CBSTRIDE = kDH * kDH + kDH;  // 4160 per (bh,chunk): ST[e][d] (4096) + z (64)
constexpr float kEPS = 1e-3f;

typedef _Float16 f16x8 __attribute__((ext_vector_type(8)));
typedef _Float16 f16x4 __attribute__((ext_vector_type(4)));
typedef float    floatx4 __attribute__((ext_vector_type(4)));

__device__ __forceinline__ void async_copy16(void* lds, const void* g) {
    __builtin_amdgcn_global_load_lds(
        (const __attribute__((address_space(1))) void*)g,
        (__attribute__((address_space(3))) void*)lds,
        16, 0, 0);
}

// ---------------------------------------------------------------------------
// fp32 -> fp16 convert of x (no transpose).  2M elems, 8 per thread.
// ---------------------------------------------------------------------------
__global__ __launch_bounds__(256)
void convert_x_kernel(const float* __restrict__ x, _Float16* __restrict__ xh)
{
    const int i = blockIdx.x * 256 + threadIdx.x;
    const float4 a = *(const float4*)(x + (size_t)i * 8);
    const float4 b = *(const float4*)(x + (size_t)i * 8 + 4);
    f16x8 o;
    o[0] = (_Float16)a.x; o[1] = (_Float16)a.y; o[2] = (_Float16)a.z; o[3] = (_Float16)a.w;
    o[4] = (_Float16)b.x; o[5] = (_Float16)b.y; o[6] = (_Float16)b.z; o[7] = (_Float16)b.w;
    *(f16x8*)(xh + (size_t)i * 8) = o;
}

// ---------------------------------------------------------------------------
// Transpose + convert weights: W[512][512] fp32 -> WT[512][512] fp16 (WT[n][k]).
// z = 0,1,2 -> Wq,Wk,Wv into fused WT[1536][512]; z = 3 -> Wo into WoT.
// ---------------------------------------------------------------------------
__global__ __launch_bounds__(256)
void convert_wT_kernel(const float* __restrict__ Wq, const float* __restrict__ Wk,
                       const float* __restrict__ Wv, const float* __restrict__ Wo,
                       _Float16* __restrict__ WT, _Float16* __restrict__ WoT)
{
    __shared__ float tile[32][33];
    const int z = blockIdx.z;
    const float* src = (z == 0) ? Wq : (z == 1) ? Wk : (z == 2) ? Wv : Wo;
    _Float16* dst = (z < 3) ? (WT + (size_t)z * 512 * 512) : WoT;
    const int r0 = blockIdx.y * 32, c0 = blockIdx.x * 32;
    const int tr = threadIdx.x >> 5, tc = threadIdx.x & 31;
    #pragma unroll
    for (int i = 0; i < 4; ++i)
        tile[tr + 8 * i][tc] = src[(size_t)(r0 + tr + 8 * i) * 512 + c0 + tc];
    __syncthreads();
    #pragma unroll
    for (int i = 0; i < 4; ++i)
        dst[(size_t)(c0 + tr + 8 * i) * 512 + r0 + tc] = (_Float16)tile[tc][tr + 8 * i];
}

// ---------------------------------------------------------------------------
// MFMA GEMM: C[M][N] = A[M][K=512] * BT[N][K]^T, fp16 in, fp32 out.
// BM=BN=128, BK=64, 256 threads (4 waves, 2x2), global_load_lds staging,
// XOR-swizzled (slot ^ row&7) source+read.
// MODE 0: qkv epilogue -> fp16 qh,kh row-major [bh][n][64] (relu+eps on q,k),
//         fp16 kTh,vTh transposed [bh][d][n].
// MODE 1: out epilogue (+bias, fp32 row-major [4096][512]).
// ---------------------------------------------------------------------------
template<int MODE>
__global__ __launch_bounds__(256)
void mfma_gemm_kernel(const _Float16* __restrict__ A,
                      const _Float16* __restrict__ BT,
                      const float* __restrict__ bo,
                      float* __restrict__ outf,
                      _Float16* __restrict__ qh,
                      _Float16* __restrict__ khb,
                      _Float16* __restrict__ kTh,
                      _Float16* __restrict__ vTh)
{
    constexpr int BM = 128, BN = 128, BK = 64, K = 512;
    __shared__ _Float16 As[BM * BK];   // 16 KB, rows of 128 B
    __shared__ _Float16 Bs[BN * BK];   // 16 KB

    const int t = threadIdx.x;
    const int l = t & 63;
    const int w = t >> 6;
    const int wm = w >> 1, wn = w & 1;
    const int m0 = blockIdx.x * BM;
    const int n0 = blockIdx.y * BN;

    const int r15 = l & 15, kq = l >> 4, sw = r15 & 7;

    floatx4 acc[4][4];
    #pragma unroll
    for (int mi = 0; mi < 4; ++mi)
        #pragma unroll
        for (int ni = 0; ni < 4; ++ni)
            acc[mi][ni] = (floatx4){0.f, 0.f, 0.f, 0.f};

    const int srow  = t >> 3;       // 0..31
    const int sslot = t & 7;        // 16B slot within 128B row

    const char* Abase = (const char*)(A + (size_t)m0 * K);
    const char* Bbase = (const char*)(BT + (size_t)n0 * K);
    char* AsB = (char*)As;
    char* BsB = (char*)Bs;

    const char* ArdB = (const char*)As + (wm * 64 + r15) * 128;
    const char* BrdB = (const char*)Bs + (wn * 64 + r15) * 128;
    const int sw0 = ((kq ^ sw) << 4);
    const int sw1 = (((4 + kq) ^ sw) << 4);

    for (int k0 = 0; k0 < K; k0 += BK) {
        #pragma unroll
        for (int i = 0; i < 4; ++i) {
            const int row = i * 32 + srow;
            const int gsl = sslot ^ (row & 7);
            async_copy16(AsB + row * 128 + sslot * 16,
                         Abase + (size_t)row * (K * 2) + k0 * 2 + gsl * 16);
            async_copy16(BsB + row * 128 + sslot * 16,
                         Bbase + (size_t)row * (K * 2) + k0 * 2 + gsl * 16);
        }
        __syncthreads();

        f16x8 af[4][2], bf[4][2];
        #pragma unroll
        for (int i = 0; i < 4; ++i) {
            af[i][0] = *(const f16x8*)(ArdB + i * 2048 + sw0);
            af[i][1] = *(const f16x8*)(ArdB + i * 2048 + sw1);
            bf[i][0] = *(const f16x8*)(BrdB + i * 2048 + sw0);
            bf[i][1] = *(const f16x8*)(BrdB + i * 2048 + sw1);
        }
        #pragma unroll
        for (int kk = 0; kk < 2; ++kk)
            #pragma unroll
            for (int mi = 0; mi < 4; ++mi)
                #pragma unroll
                for (int ni = 0; ni < 4; ++ni)
                    acc[mi][ni] = __builtin_amdgcn_mfma_f32_16x16x32_f16(
                        af[mi][kk], bf[ni][kk], acc[mi][ni], 0, 0, 0);
        __syncthreads();
    }

    // Epilogue.  C fragment: row = kq*4 + r, col = r15 (within each 16x16).
    if (MODE == 0) {
        #pragma unroll
        for (int ni = 0; ni < 4; ++ni) {
            const int col = n0 + wn * 64 + ni * 16 + r15;   // 0..1535
            const int which = col >> 9;
            const int h = (col >> 6) & 7, e = col & 63;
            #pragma unroll
            for (int mi = 0; mi < 4; ++mi) {
                const int row0 = m0 + wm * 64 + mi * 16 + kq * 4;
                const int b = row0 >> 11, nn = row0 & 2047;
                const int bh = b * 8 + h;
                float vv[4];
                #pragma unroll
                for (int r = 0; r < 4; ++r) {
                    float v = acc[mi][ni][r];
                    if (which < 2) v = fmaxf(v, 0.f) + kEPS;
                    vv[r] = v;
                }
                if (which == 0) {
                    #pragma unroll
                    for (int r = 0; r < 4; ++r)
                        qh[((size_t)bh * kN + nn + r) * 64 + e] = (_Float16)vv[r];
                } else if (which == 1) {
                    #pragma unroll
                    for (int r = 0; r < 4; ++r)
                        khb[((size_t)bh * kN + nn + r) * 64 + e] = (_Float16)vv[r];
                    f16x4 t4;
                    t4[0] = (_Float16)vv[0]; t4[1] = (_Float16)vv[1];
                    t4[2] = (_Float16)vv[2]; t4[3] = (_Float16)vv[3];
                    *(f16x4*)(kTh + ((size_t)bh * 64 + e) * kN + nn) = t4;
                } else {
                    f16x4 t4;
                    t4[0] = (_Float16)vv[0]; t4[1] = (_Float16)vv[1];
                    t4[2] = (_Float16)vv[2]; t4[3] = (_Float16)vv[3];
                    *(f16x4*)(vTh + ((size_t)bh * 64 + e) * kN + nn) = t4;
                }
            }
        }
    } else {
        #pragma unroll
        for (int ni = 0; ni < 4; ++ni) {
            const int col = n0 + wn * 64 + ni * 16 + r15;
            const float bias = bo[col];
            #pragma unroll
            for (int mi = 0; mi < 4; ++mi) {
                const int row = m0 + wm * 64 + mi * 16 + kq * 4;
                #pragma unroll
                for (int r = 0; r < 4; ++r)
                    outf[(size_t)(row + r) * 512 + col] = acc[mi][ni][r] + bias;
            }
        }
    }
}

// ---------------------------------------------------------------------------
// chunk_sum (MFMA): ST_c[e][d] = sum_n v[n][e] k[n][d]  (A=vT, B=kT, K-dim=n=64)
// z_c[d] = sum_n k[n][d].  grid (NCH, BH), block 256 (4 waves, wave w = e-rows w*16..).
// ---------------------------------------------------------------------------
__global__ __launch_bounds__(256)
void chunk_sum_kernel(const _Float16* __restrict__ kTh, const _Float16* __restrict__ vTh,
                      float* __restrict__ cbuf)
{
    const int ch = blockIdx.x, bh = blockIdx.y;
    const int t = threadIdx.x, l = t & 63, w = t >> 6;
    const int r15 = l & 15, kq = l >> 4;

    const _Float16* vbase = vTh + (size_t)bh * 64 * kN + ch * 64;
    const _Float16* kbase = kTh + (size_t)bh * 64 * kN + ch * 64;

    f16x8 av[2], bk[4][2];
    #pragma unroll
    for (int kk = 0; kk < 2; ++kk) {
        av[kk] = *(const f16x8*)(vbase + (size_t)(w * 16 + r15) * kN + kk * 32 + kq * 8);
        #pragma unroll
        for (int ni = 0; ni < 4; ++ni)
            bk[ni][kk] = *(const f16x8*)(kbase + (size_t)(ni * 16 + r15) * kN + kk * 32 + kq * 8);
    }
    floatx4 acc[4];
    #pragma unroll
    for (int ni = 0; ni < 4; ++ni) acc[ni] = (floatx4){0.f, 0.f, 0.f, 0.f};
    #pragma unroll
    for (int kk = 0; kk < 2; ++kk)
        #pragma unroll
        for (int ni = 0; ni < 4; ++ni)
            acc[ni] = __builtin_amdgcn_mfma_f32_16x16x32_f16(av[kk], bk[ni][kk], acc[ni], 0, 0, 0);

    float* out = cbuf + ((size_t)bh * NCH + ch) * CBSTRIDE;
    #pragma unroll
    for (int ni = 0; ni < 4; ++ni)
        #pragma unroll
        for (int r = 0; r < 4; ++r)
            out[(size_t)(w * 16 + kq * 4 + r) * 64 + ni * 16 + r15] = acc[ni][r];

    if (t < 64) {
        const _Float16* kp = kbase + (size_t)t * kN;
        float z = 0.f;
        #pragma unroll
        for (int j = 0; j < 8; ++j) {
            f16x8 v8 = *(const f16x8*)(kp + j * 8);
            #pragma unroll
            for (int u = 0; u < 8; ++u) z += (float)v8[u];
        }
        out[4096 + t] = z;
    }
}

// ---------------------------------------------------------------------------
// exclusive prefix over chunks; writes fp16 STpre (B-operand layout [e][d])
// and fp32 z_pre.  grid (17, BH), block 256.
// ---------------------------------------------------------------------------
__global__ __launch_bounds__(256)
void prefix_kernel(const float* __restrict__ cbuf, _Float16* __restrict__ spre16,
                   float* __restrict__ zpre)
{
    const int bh = blockIdx.y;
    const int i = blockIdx.x * 256 + threadIdx.x;
    if (i >= CBSTRIDE) return;
    const float* src = cbuf + (size_t)bh * NCH * CBSTRIDE + i;
    _Float16* dst = spre16 + (size_t)bh * NCH * CBSTRIDE + i;
    float* zp = zpre + (size_t)bh * NCH * 64;
    const bool isz = (i >= 4096);
    float vals[NCH];
    #pragma unroll
    for (int c = 0; c < NCH; ++c) vals[c] = src[(size_t)c * CBSTRIDE];
    float a = 0.f;
    #pragma unroll
    for (int c = 0; c < NCH; ++c) {
        dst[(size_t)c * CBSTRIDE] = (_Float16)a;
        if (isz) zp[c * 64 + (i - 4096)] = a;
        a += vals[c];
    }
}

// ---------------------------------------------------------------------------
// chunk_out (MFMA): scores = QK^T (masked) -> P fp16 in swizzled LDS,
// O = P V + Q STpre, den = rowsum(P) + q.z_pre, attn = O/den (fp16).
// grid (NCH, BH), block 256 (wave w = query rows w*16..w*16+15).
// ---------------------------------------------------------------------------
__global__ __launch_bounds__(256)
void chunk_out_kernel(const _Float16* __restrict__ qh, const _Float16* __restrict__ khb,
                      const _Float16* __restrict__ vTh, const _Float16* __restrict__ spre16,
                      const float* __restrict__ zpre, _Float16* __restrict__ attnh)
{
    const int ch = blockIdx.x, bh = blockIdx.y;
    const int t = threadIdx.x, l = t & 63, w = t >> 6;
    const int r15 = l & 15, kq = l >> 4;

    __shared__ _Float16 Plds[64 * 64];   // swizzled rows of 128 B
    __shared__ float denp[64];
    __shared__ float denf[64];

    const size_t rowbase = (size_t)bh * kN + ch * 64;

    // Phase 1: scores = Q K^T   (A rows = w*16 + r15, K-dim = d = 64)
    f16x8 aq[2], bk[4][2];
    #pragma unroll
    for (int kk = 0; kk < 2; ++kk) {
        aq[kk] = *(const f16x8*)(qh + (rowbase + w * 16 + r15) * 64 + kk * 32 + kq * 8);
        #pragma unroll
        for (int ni = 0; ni < 4; ++ni)
            bk[ni][kk] = *(const f16x8*)(khb + (rowbase + ni * 16 + r15) * 64 + kk * 32 + kq * 8);
    }
    floatx4 sacc[4];
    #pragma unroll
    for (int ni = 0; ni < 4; ++ni) sacc[ni] = (floatx4){0.f, 0.f, 0.f, 0.f};
    #pragma unroll
    for (int kk = 0; kk < 2; ++kk)
        #pragma unroll
        for (int ni = 0; ni < 4; ++ni)
            sacc[ni] = __builtin_amdgcn_mfma_f32_16x16x32_f16(aq[kk], bk[ni][kk], sacc[ni], 0, 0, 0);

    // mask (m <= qn), rowsum, P -> swizzled LDS fp16
    const int qrow = w * 16 + kq * 4;
    float psum[4] = {0.f, 0.f, 0.f, 0.f};
    #pragma unroll
    for (int ni = 0; ni < 4; ++ni) {
        const int m = ni * 16 + r15;
        #pragma unroll
        for (int r = 0; r < 4; ++r) {
            const int row = qrow + r;
            const float v = (m <= row) ? sacc[ni][r] : 0.f;
            psum[r] += v;
            const int byte = row * 128 + ((((unsigned)m >> 3) ^ (row & 7)) << 4) + (m & 7) * 2;
            *(_Float16*)((char*)Plds + byte) = (_Float16)v;
        }
    }
    #pragma unroll
    for (int r = 0; r < 4; ++r) {
        float p = psum[r];
        p += __shfl_xor(p, 1, 16);
        p += __shfl_xor(p, 2, 16);
        p += __shfl_xor(p, 4, 16);
        p += __shfl_xor(p, 8, 16);
        if (r15 == 0) denp[qrow + r] = p;
    }
    __syncthreads();

    // den finalize (64 threads)
    if (t < 64) {
        const _Float16* qp = qh + (rowbase + t) * 64;
        const float* zp = zpre + ((size_t)bh * NCH + ch) * 64;
        float s = denp[t];
        #pragma unroll
        for (int j = 0; j < 8; ++j) {
            f16x8 q8 = *(const f16x8*)(qp + j * 8);
            #pragma unroll
            for (int u = 0; u < 8; ++u) s += (float)q8[u] * zp[j * 8 + u];
        }
        denf[t] = 1.0f / s;
    }

    // Phase 2: O = P V + Q STpre
    f16x8 ap[2], bv[4][2], bs[4][2];
    #pragma unroll
    for (int km = 0; km < 2; ++km)
        ap[km] = *(const f16x8*)((char*)Plds + (w * 16 + r15) * 128 +
                                 (((km * 4 + kq) ^ (r15 & 7)) << 4));
    #pragma unroll
    for (int ni = 0; ni < 4; ++ni) {
        #pragma unroll
        for (int km = 0; km < 2; ++km)
            bv[ni][km] = *(const f16x8*)(vTh + ((size_t)bh * 64 + ni * 16 + r15) * kN +
                                         ch * 64 + km * 32 + kq * 8);
    }
    const _Float16* sp = spre16 + ((size_t)bh * NCH + ch) * CBSTRIDE;
    #pragma unroll
    for (int ni = 0; ni < 4; ++ni)
        #pragma unroll
        for (int kd = 0; kd < 2; ++kd)
            bs[ni][kd] = *(const f16x8*)(sp + (size_t)(ni * 16 + r15) * 64 + kd * 32 + kq * 8);

    floatx4 oacc[4];
    #pragma unroll
    for (int ni = 0; ni < 4; ++ni) oacc[ni] = (floatx4){0.f, 0.f, 0.f, 0.f};
    #pragma unroll
    for (int km = 0; km < 2; ++km)
        #pragma unroll
        for (int ni = 0; ni < 4; ++ni)
            oacc[ni] = __builtin_amdgcn_mfma_f32_16x16x32_f16(ap[km], bv[ni][km], oacc[ni], 0, 0, 0);
    #pragma unroll
    for (int kd = 0; kd < 2; ++kd)
        #pragma unroll
        for (int ni = 0; ni < 4; ++ni)
            oacc[ni] = __builtin_amdgcn_mfma_f32_16x16x32_f16(aq[kd], bs[ni][kd], oacc[ni], 0, 0, 0);
    __syncthreads();   // denf ready

    const int b = bh >> 3, h = bh & 7;
    #pragma unroll
    for (int ni = 0; ni < 4; ++ni) {
        const int e = ni * 16 + r15;
        #pragma unroll
        for (int r = 0; r < 4; ++r) {
            const int qn = qrow + r;
            const float ov = oacc[ni][r] * denf[qn];
            attnh[((size_t)(b * kN + ch * 64 + qn)) * 512 + h * 64 + e] = (_Float16)ov;
        }
    }
}

// ---------------------------------------------------------------------------
extern "C" void kernel_launch(void* const* d_in, const int* in_sizes, int n_in,
                              void* d_out, int out_size, void* d_ws, size_t ws_size,
                              hipStream_t stream)
{
    const float* x  = (const float*)d_in[0];
    const float* Wq = (const float*)d_in[1];
    const float* Wk = (const float*)d_in[2];
    const float* Wv = (const float*)d_in[3];
    const float* Wo = (const float*)d_in[4];
    const float* bo = (const float*)d_in[5];
    float* out = (float*)d_out;

    char* ws = (char*)d_ws;
    _Float16* qh     = (_Float16*)(ws + 0);          // 4,194,304 B [bh][n][64]
    _Float16* khb    = (_Float16*)(ws + 4194304);    // 4,194,304 B [bh][n][64]
    _Float16* kTh    = (_Float16*)(ws + 8388608);    // 4,194,304 B [bh][64][n]
    _Float16* vTh    = (_Float16*)(ws + 12582912);   // 4,194,304 B [bh][64][n]
    float*    cbuf   = (float*)(ws + 16777216);      // 8,519,680 B [bh][ch][4160] f32
    _Float16* spre16 = (_Float16*)(ws + 25296896);   // 4,259,840 B [bh][ch][4160] f16
    float*    zpre   = (float*)(ws + 29556736);      //   131,072 B [bh][ch][64] f32
    _Float16* xh     = (_Float16*)(ws + 29687808);   // 4,194,304 B [4096][512] f16
    _Float16* WT     = (_Float16*)(ws + 33882112);   // 1,572,864 B [1536][512] f16
    _Float16* WoT    = (_Float16*)(ws + 35454976);   //   524,288 B [512][512] f16
    _Float16* attnh  = xh;                           // alias: xh dead after qkv GEMM

    convert_x_kernel<<<1024, 256, 0, stream>>>(x, xh);
    convert_wT_kernel<<<dim3(16, 16, 4), 256, 0, stream>>>(Wq, Wk, Wv, Wo, WT, WoT);
    mfma_gemm_kernel<0><<<dim3(NROWS / 128, 12), 256, 0, stream>>>(
        xh, WT, nullptr, nullptr, qh, khb, kTh, vTh);
    chunk_sum_kernel<<<dim3(NCH, kBH), 256, 0, stream>>>(kTh, vTh, cbuf);
    prefix_kernel<<<dim3(17, kBH), 256, 0, stream>>>(cbuf, spre16, zpre);
    chunk_out_kernel<<<dim3(NCH, kBH), 256, 0, stream>>>(qh, khb, vTh, spre16, zpre, attnh);
    mfma_gemm_kernel<1><<<dim3(NROWS / 128, 4), 256, 0, stream>>>(
        attnh, WoT, bo, out, nullptr, nullptr, nullptr, nullptr);
}